// Round 6
// baseline (298.860 us; speedup 1.0000x reference)
//
#include <hip/hip_runtime.h>
#include <stdint.h>

#define NROWS 1024
#define CDIM  4096
#define KDIM  16384
#define SIDE  128

typedef __attribute__((ext_vector_type(8))) short short8;
typedef __attribute__((ext_vector_type(4))) float f32x4;

static __device__ __forceinline__ unsigned short f2bf(float f) {
  unsigned u = __float_as_uint(f);
  u += 0x7fffu + ((u >> 16) & 1u);   // round-to-nearest-even
  return (unsigned short)(u >> 16);
}
static __device__ __forceinline__ float bf2f(unsigned short h) {
  return __uint_as_float(((unsigned)h) << 16);
}

#define GLOAD_LDS16(g, l)                                                     \
  __builtin_amdgcn_global_load_lds(                                           \
      (const __attribute__((address_space(1))) void*)(g),                     \
      (__attribute__((address_space(3))) void*)(l), 16, 0, 0)

// ---------- zero w2 ----------
__global__ void k_zero(float* __restrict__ w2) {
  w2[blockIdx.x * 256 + threadIdx.x] = 0.f;
}

// ---------- weights: f32 [c][k] -> bf16 hi/lo transposed [k][c]; fused w2 ----
__global__ __launch_bounds__(256) void k_wconv(const float* __restrict__ w,
                                               unsigned short* __restrict__ whT,
                                               unsigned short* __restrict__ wlT,
                                               float* __restrict__ w2) {
  __shared__ float T[64][65];
  const int k0 = blockIdx.x * 64, c0 = blockIdx.y * 64;
  const int t = threadIdx.x;
#pragma unroll
  for (int i = 0; i < 4; i++) {
    int e = i * 1024 + t * 4;
    int cr = e >> 6, kc = e & 63;
    float4 v = *(const float4*)(w + (size_t)(c0 + cr) * KDIM + k0 + kc);
    T[cr][kc] = v.x; T[cr][kc + 1] = v.y; T[cr][kc + 2] = v.z; T[cr][kc + 3] = v.w;
  }
  __syncthreads();
#pragma unroll
  for (int i = 0; i < 4; i++) {
    int e = i * 1024 + t * 4;
    int kr = e >> 6, cc = e & 63;
    ushort4 hv, lv;
    float f0 = T[cc + 0][kr], f1 = T[cc + 1][kr];
    float f2 = T[cc + 2][kr], f3 = T[cc + 3][kr];
    hv.x = f2bf(f0); lv.x = f2bf(f0 - bf2f(hv.x));
    hv.y = f2bf(f1); lv.y = f2bf(f1 - bf2f(hv.y));
    hv.z = f2bf(f2); lv.z = f2bf(f2 - bf2f(hv.z));
    hv.w = f2bf(f3); lv.w = f2bf(f3 - bf2f(hv.w));
    size_t off = (size_t)(k0 + kr) * CDIM + c0 + cc;
    *(ushort4*)(whT + off) = hv;
    *(ushort4*)(wlT + off) = lv;
    float s = f0 * f0 + f1 * f1 + f2 * f2 + f3 * f3;
#pragma unroll
    for (int off2 = 8; off2 > 0; off2 >>= 1) s += __shfl_down(s, off2);
    if ((t & 15) == 0) atomicAdd(&w2[k0 + kr], s);
  }
}

// ---------- x: f32 [n][c] -> bf16 ----------
__global__ __launch_bounds__(256) void k_xconv(const float* __restrict__ x,
                                               unsigned short* __restrict__ xh) {
  size_t i = ((size_t)blockIdx.x * 256 + threadIdx.x) * 4;
  float4 v = *(const float4*)(x + i);
  ushort4 hv;
  hv.x = f2bf(v.x); hv.y = f2bf(v.y); hv.z = f2bf(v.z); hv.w = f2bf(v.w);
  *(ushort4*)(xh + i) = hv;
}

// ---------- x2[n] = sum_c x^2 ----------
__global__ void k_x2(const float* __restrict__ x, float* __restrict__ x2) {
  const int n = blockIdx.x, l = threadIdx.x;  // 64 threads
  const float* row = x + (size_t)n * CDIM;
  float s = 0.f;
#pragma unroll 4
  for (int i = 0; i < 16; i++) {
    float4 v = *(const float4*)(row + (i * 64 + l) * 4);
    s += v.x * v.x + v.y * v.y + v.z * v.z + v.w * v.w;
  }
#pragma unroll
  for (int off = 32; off > 0; off >>= 1) s += __shfl_down(s, off);
  if (l == 0) x2[n] = s;
}

// ---------- main MFMA GEMM: BM=BN=256, BK=64, 8 waves (2M x 4N) ----------
// m201-style phased schedule: 4 phases per K-tile, each phase =
// {ds_read subtile || stage 1 half-tile} -> barrier -> lgkmcnt(0) ->
// setprio(1) 16 MFMA setprio(0) -> barrier. vmcnt(4) only at P1/P3 (T4).
// LDS: 2 buffers x [A-kh0|A-kh1|B-kh0|B-kh1] of 16KB, 64B rows ->
// fragment reads are contiguous 1KB blocks (bank-uniform, no swizzle).
__global__ __launch_bounds__(512, 2) void k_gemm(
    const unsigned short* __restrict__ xh,
    const unsigned short* __restrict__ whT,
    const float* __restrict__ x2, const float* __restrict__ w2,
    float* __restrict__ out) {
  extern __shared__ char smem[];  // 131072 B
  const int t = threadIdx.x;
  const int b = blockIdx.x;
  const int L = (b & 7) * 32 + (b >> 3);   // XCD-bijective (256 wgs)
  const int m0 = (L & 3) * 256, n0 = (L >> 2) * 256;
  const int lane = t & 63, wid = t >> 6;
  const int wrow = (wid >> 2) * 128;   // wave M-half: 0 or 128
  const int wcol = (wid & 3) * 64;     // wave N-quarter
  const int rlo = lane & 15;
  const int kg16 = (lane >> 4) * 16;   // k-group byte offset in 64B row

  // stage geometry: thread covers rows rS and rS+128 of a half-tile
  const int rS = t >> 2;               // 0..127
  const int cbS = (t & 3) * 8;         // element col 0..24 within k-half
  const uint32_t ldst = (uint32_t)wid * 1024;

  // fragment read bases (byte offsets inside one 64KB buffer)
  const uint32_t aRB = (uint32_t)(wrow + rlo) * 64 + kg16;          // A-kh0
  const uint32_t bRB = 32768u + (uint32_t)(wcol + rlo) * 64 + kg16; // B-kh0

  f32x4 acc[8][4];
#pragma unroll
  for (int m = 0; m < 8; m++)
#pragma unroll
    for (int n = 0; n < 4; n++) acc[m][n] = (f32x4){0.f, 0.f, 0.f, 0.f};

  // S: 0=A-kh0, 1=A-kh1, 2=B-kh0, 3=B-kh1 (16KB each)
#define STAGE_HALF(tt, S)                                                     \
  do {                                                                        \
    if ((tt) < 64) {                                                          \
      char* dst = smem + ((tt) & 1) * 65536 + (S) * 16384;                    \
      const unsigned short* gb = ((S) >= 2 ? whT : xh);                       \
      const int gr0 = ((S) >= 2 ? n0 : m0);                                   \
      const int gc0 = (tt) * 64 + ((S) & 1) * 32;                             \
      _Pragma("unroll")                                                       \
      for (int i_ = 0; i_ < 2; i_++) {                                        \
        size_t g = (size_t)(gr0 + i_ * 128 + rS) * CDIM + gc0 + cbS;          \
        GLOAD_LDS16(gb + g, dst + i_ * 8192 + ldst);                          \
      }                                                                       \
    }                                                                         \
  } while (0)

#define DO_MFMA(mh)                                                           \
  do {                                                                        \
    __builtin_amdgcn_s_barrier();                                             \
    asm volatile("s_waitcnt lgkmcnt(0)" ::: "memory");                        \
    __builtin_amdgcn_sched_barrier(0);                                        \
    __builtin_amdgcn_s_setprio(1);                                            \
    _Pragma("unroll")                                                         \
    for (int m_ = 0; m_ < 4; m_++)                                            \
      _Pragma("unroll")                                                       \
      for (int n_ = 0; n_ < 4; n_++)                                          \
        acc[(mh) * 4 + m_][n_] = __builtin_amdgcn_mfma_f32_16x16x32_bf16(     \
            af[m_], bf[n_], acc[(mh) * 4 + m_][n_], 0, 0, 0);                 \
    __builtin_amdgcn_s_setprio(0);                                            \
    __builtin_amdgcn_s_barrier();                                             \
  } while (0)

  // prologue: stage all 4 half-tiles of tile 0; drain once; sync
  STAGE_HALF(0, 0);
  STAGE_HALF(0, 2);
  STAGE_HALF(0, 1);
  STAGE_HALF(0, 3);
  asm volatile("s_waitcnt vmcnt(0)" ::: "memory");
  __builtin_amdgcn_s_barrier();

  for (int tl = 0; tl < 64; ++tl) {
    const uint32_t dbase = (uint32_t)(tl & 1) * 65536;
    short8 af[4], bf[4];
    // ---- P0: ks0, m0-3 (8 ds_reads) ; stage A-kh0(t+1)
#pragma unroll
    for (int n = 0; n < 4; n++)
      bf[n] = *(const short8*)(smem + dbase + bRB + n * 1024);
#pragma unroll
    for (int m = 0; m < 4; m++)
      af[m] = *(const short8*)(smem + dbase + aRB + m * 1024);
    STAGE_HALF(tl + 1, 0);
    DO_MFMA(0);
    // ---- P1: ks0, m4-7 (4 ds_reads) ; stage B-kh0(t+1) ; vmcnt
#pragma unroll
    for (int m = 0; m < 4; m++)
      af[m] = *(const short8*)(smem + dbase + aRB + (m + 4) * 1024);
    STAGE_HALF(tl + 1, 2);
    if (tl < 63) {
      asm volatile("s_waitcnt vmcnt(4)" ::: "memory");  // kh1(t) landed
    } else {
      asm volatile("s_waitcnt vmcnt(0)" ::: "memory");  // tail
    }
    DO_MFMA(1);
    // ---- P2: ks1, m0-3 (8 ds_reads) ; stage A-kh1(t+1)
#pragma unroll
    for (int n = 0; n < 4; n++)
      bf[n] = *(const short8*)(smem + dbase + 16384 + bRB + n * 1024);
#pragma unroll
    for (int m = 0; m < 4; m++)
      af[m] = *(const short8*)(smem + dbase + 16384 + aRB + m * 1024);
    STAGE_HALF(tl + 1, 1);
    DO_MFMA(0);
    // ---- P3: ks1, m4-7 (4 ds_reads) ; stage B-kh1(t+1) ; vmcnt
#pragma unroll
    for (int m = 0; m < 4; m++)
      af[m] = *(const short8*)(smem + dbase + 16384 + aRB + (m + 4) * 1024);
    STAGE_HALF(tl + 1, 3);
    if (tl < 63) {
      asm volatile("s_waitcnt vmcnt(4)" ::: "memory");  // kh0(t+1) landed
    }
    DO_MFMA(1);
  }
#undef STAGE_HALF
#undef DO_MFMA

  // epilogue: norms2 ~= max(x2 + w2 - 2*xw, 0)
  float w2v[4];
#pragma unroll
  for (int n = 0; n < 4; n++) w2v[n] = w2[n0 + wcol + n * 16 + rlo];
#pragma unroll
  for (int m = 0; m < 8; m++) {
#pragma unroll
    for (int j = 0; j < 4; j++) {
      int row = m0 + wrow + m * 16 + (lane >> 4) * 4 + j;
      float xr = x2[row];
      float* orow = out + (size_t)row * KDIM;
#pragma unroll
      for (int n = 0; n < 4; n++) {
        int col = n0 + wcol + n * 16 + rlo;
        float v = xr + w2v[n] - 2.0f * acc[m][n][j];
        orow[col] = v < 0.f ? 0.f : v;
      }
    }
  }
}

// ---------- fallback fp32 GEMM (exact), used only if ws too small ----------
__global__ __launch_bounds__(256) void k_fb(const float* __restrict__ x,
                                            const float* __restrict__ w,
                                            float* __restrict__ out) {
  __shared__ float xs[16][65];
  __shared__ float wsm[16][65];
  const int t = threadIdx.x;
  const int n0 = blockIdx.x * 64, k0 = blockIdx.y * 64;
  const int tx = t & 15, ty = t >> 4;
  float acc[4][4];
#pragma unroll
  for (int a = 0; a < 4; a++)
#pragma unroll
    for (int b = 0; b < 4; b++) acc[a][b] = 0.f;
  for (int c0 = 0; c0 < CDIM; c0 += 16) {
#pragma unroll
    for (int i = 0; i < 4; i++) {
      int e = i * 256 + t;
      int nl = e >> 4, cl = e & 15;
      xs[cl][nl] = x[(size_t)(n0 + nl) * CDIM + c0 + cl];
    }
#pragma unroll
    for (int i = 0; i < 4; i++) {
      int e = i * 256 + t;
      int cl = e >> 6, kl = e & 63;
      wsm[cl][kl] = w[(size_t)(c0 + cl) * KDIM + k0 + kl];
    }
    __syncthreads();
#pragma unroll
    for (int c = 0; c < 16; c++)
#pragma unroll
      for (int a = 0; a < 4; a++) {
        float xa = xs[c][ty * 4 + a];
#pragma unroll
        for (int b = 0; b < 4; b++) {
          float d = wsm[c][tx * 4 + b] - xa;
          acc[a][b] += d * d;
        }
      }
    __syncthreads();
  }
#pragma unroll
  for (int a = 0; a < 4; a++)
#pragma unroll
    for (int b = 0; b < 4; b++)
      out[(size_t)(n0 + ty * 4 + a) * KDIM + k0 + tx * 4 + b] = acc[a][b];
}

// ---------- per-row: min -> candidates -> exact refine -> RBF scale ----------
__global__ __launch_bounds__(256) void k_row(
    float* __restrict__ out, const float* __restrict__ stdp,
    const float* __restrict__ x, const unsigned short* __restrict__ whT,
    const unsigned short* __restrict__ wlT, const float* __restrict__ w2) {
  const int n = blockIdx.x, t = threadIdx.x;
  __shared__ alignas(16) float er[SIDE];
  __shared__ alignas(16) float ec[SIDE];
  __shared__ float rv[4];
  __shared__ float s_red[4];
  __shared__ int cand[128];
  __shared__ int s_ncand;
  __shared__ int s_bmu;
  __shared__ float s_inv;
  float* row = out + (size_t)n * KDIM;

  // pass 1: block-min of approximate scores
  float bv = 3.4e38f;
#pragma unroll 4
  for (int i = 0; i < 16; i++) {
    float4 v = *(const float4*)(row + (t + i * 256) * 4);
    bv = fminf(fminf(fminf(bv, v.x), fminf(v.y, v.z)), v.w);
  }
#pragma unroll
  for (int off = 32; off > 0; off >>= 1) bv = fminf(bv, __shfl_down(bv, off));
  if ((t & 63) == 0) rv[t >> 6] = bv;
  if (t == 0) s_ncand = 0;
  __syncthreads();
  const float thr = fminf(fminf(rv[0], rv[1]), fminf(rv[2], rv[3])) + 0.05f;

  // pass 2: collect candidate indices within the safety window
#pragma unroll 4
  for (int i = 0; i < 16; i++) {
    int k = (t + i * 256) * 4;
    float4 v = *(const float4*)(row + k);
    if (v.x <= thr) { int j = atomicAdd(&s_ncand, 1); if (j < 128) cand[j] = k; }
    if (v.y <= thr) { int j = atomicAdd(&s_ncand, 1); if (j < 128) cand[j] = k + 1; }
    if (v.z <= thr) { int j = atomicAdd(&s_ncand, 1); if (j < 128) cand[j] = k + 2; }
    if (v.w <= thr) { int j = atomicAdd(&s_ncand, 1); if (j < 128) cand[j] = k + 3; }
  }
  __syncthreads();
  int nc = s_ncand < 128 ? s_ncand : 128;

  // refine: exact score = w2[k] - 2 * dot(x_f32, wh+wl) per candidate
  float best = 3.4e38f;
  int bestk = 0x7fffffff;
  const float* xr = x + (size_t)n * CDIM;
  for (int j = 0; j < nc; j++) {
    const int k = cand[j];
    const unsigned short* wh = whT + (size_t)k * CDIM;
    const unsigned short* wl = wlT + (size_t)k * CDIM;
    float s = 0.f;
#pragma unroll
    for (int ii = 0; ii < 2; ii++) {
      int c = (ii * 256 + t) * 8;
      short8 h8 = *(const short8*)(wh + c);
      short8 l8 = *(const short8*)(wl + c);
      float4 xa = *(const float4*)(xr + c);
      float4 xb = *(const float4*)(xr + c + 4);
      s += xa.x * (bf2f((unsigned short)h8[0]) + bf2f((unsigned short)l8[0]));
      s += xa.y * (bf2f((unsigned short)h8[1]) + bf2f((unsigned short)l8[1]));
      s += xa.z * (bf2f((unsigned short)h8[2]) + bf2f((unsigned short)l8[2]));
      s += xa.w * (bf2f((unsigned short)h8[3]) + bf2f((unsigned short)l8[3]));
      s += xb.x * (bf2f((unsigned short)h8[4]) + bf2f((unsigned short)l8[4]));
      s += xb.y * (bf2f((unsigned short)h8[5]) + bf2f((unsigned short)l8[5]));
      s += xb.z * (bf2f((unsigned short)h8[6]) + bf2f((unsigned short)l8[6]));
      s += xb.w * (bf2f((unsigned short)h8[7]) + bf2f((unsigned short)l8[7]));
    }
#pragma unroll
    for (int off = 32; off > 0; off >>= 1) s += __shfl_down(s, off);
    if ((t & 63) == 0) s_red[t >> 6] = s;
    __syncthreads();
    if (t == 0) {
      float dot = s_red[0] + s_red[1] + s_red[2] + s_red[3];
      float sc = w2[k] - 2.0f * dot;
      if (sc < best || (sc == best && k < bestk)) { best = sc; bestk = k; }
    }
    __syncthreads();
  }
  if (t == 0) s_bmu = bestk;
  __syncthreads();

  const int bmu = s_bmu;
  const float sd = stdp[0];
  const float inv2s2 = -0.5f / (sd * sd);
  const float rr = (float)(bmu >> 7), ccol = (float)(bmu & 127);
  if (t < 128) {
    float d = (float)t - rr;
    er[t] = expf(d * d * inv2s2);
  } else {
    int j = t - 128;
    float d = (float)j - ccol;
    ec[j] = expf(d * d * inv2s2);
  }
  __syncthreads();
  if (t == 0) {
    float Sr = 0.f, Sc = 0.f;
    for (int i = 0; i < SIDE; i++) { Sr += er[i]; Sc += ec[i]; }
    s_inv = 1.0f / (Sr * Sc);
  }
  __syncthreads();
  const float inv = s_inv;
#pragma unroll 4
  for (int i = 0; i < 16; i++) {
    int k = (t + i * 256) * 4;
    float4 v = *(const float4*)(row + k);
    float e_r = er[k >> 7] * inv;
    const float4 e4 = *(const float4*)(&ec[k & 127]);
    v.x *= e_r * e4.x;
    v.y *= e_r * e4.y;
    v.z *= e_r * e4.z;
    v.w *= e_r * e4.w;
    *(float4*)(row + k) = v;
  }
}

// ---------- fallback per-row (exact norms2 from k_fb) ----------
__global__ __launch_bounds__(256) void k_row_fb(float* __restrict__ out,
                                                const float* __restrict__ stdp) {
  const int n = blockIdx.x, t = threadIdx.x;
  __shared__ alignas(16) float er[SIDE];
  __shared__ alignas(16) float ec[SIDE];
  __shared__ float rv[4];
  __shared__ int ri[4];
  __shared__ float s_inv;
  __shared__ int s_bmu;
  float* row = out + (size_t)n * KDIM;

  float bv = 3.4e38f;
  int bi = 0;
#pragma unroll 4
  for (int i = 0; i < 16; i++) {
    int k = (t + i * 256) * 4;
    float4 v = *(const float4*)(row + k);
    if (v.x < bv) { bv = v.x; bi = k; }
    if (v.y < bv) { bv = v.y; bi = k + 1; }
    if (v.z < bv) { bv = v.z; bi = k + 2; }
    if (v.w < bv) { bv = v.w; bi = k + 3; }
  }
#pragma unroll
  for (int off = 32; off > 0; off >>= 1) {
    float ov = __shfl_down(bv, off);
    int oi = __shfl_down(bi, off);
    if (ov < bv || (ov == bv && oi < bi)) { bv = ov; bi = oi; }
  }
  if ((t & 63) == 0) { rv[t >> 6] = bv; ri[t >> 6] = bi; }
  __syncthreads();
  if (t == 0) {
    for (int i = 1; i < 4; i++)
      if (rv[i] < bv || (rv[i] == bv && ri[i] < bi)) { bv = rv[i]; bi = ri[i]; }
    s_bmu = bi;
  }
  __syncthreads();
  const int bmu = s_bmu;
  const float sd = stdp[0];
  const float inv2s2 = -0.5f / (sd * sd);
  const float rr = (float)(bmu >> 7), ccol = (float)(bmu & 127);
  if (t < 128) {
    float d = (float)t - rr;
    er[t] = expf(d * d * inv2s2);
  } else {
    int j = t - 128;
    float d = (float)j - ccol;
    ec[j] = expf(d * d * inv2s2);
  }
  __syncthreads();
  if (t == 0) {
    float Sr = 0.f, Sc = 0.f;
    for (int i = 0; i < SIDE; i++) { Sr += er[i]; Sc += ec[i]; }
    s_inv = 1.0f / (Sr * Sc);
  }
  __syncthreads();
  const float inv = s_inv;
#pragma unroll 4
  for (int i = 0; i < 16; i++) {
    int k = (t + i * 256) * 4;
    float4 v = *(const float4*)(row + k);
    float e_r = er[k >> 7] * inv;
    const float4 e4 = *(const float4*)(&ec[k & 127]);
    v.x *= e_r * e4.x;
    v.y *= e_r * e4.y;
    v.z *= e_r * e4.z;
    v.w *= e_r * e4.w;
    *(float4*)(row + k) = v;
  }
}

extern "C" void kernel_launch(void* const* d_in, const int* in_sizes, int n_in,
                              void* d_out, int out_size, void* d_ws, size_t ws_size,
                              hipStream_t stream) {
  (void)in_sizes; (void)n_in; (void)out_size;
  const float* x = (const float*)d_in[0];
  const float* w = (const float*)d_in[1];
  const float* stdp = (const float*)d_in[2];
  float* out = (float*)d_out;

  const size_t sz_wT = (size_t)KDIM * CDIM * sizeof(unsigned short);  // 128 MiB each
  const size_t sz_x  = (size_t)NROWS * CDIM * sizeof(unsigned short); // 8 MiB
  const size_t need = 2 * sz_wT + sz_x + (size_t)NROWS * 4 + (size_t)KDIM * 4;

  if (ws_size >= need) {
    char* p = (char*)d_ws;
    unsigned short* whT = (unsigned short*)p; p += sz_wT;
    unsigned short* wlT = (unsigned short*)p; p += sz_wT;
    unsigned short* xh  = (unsigned short*)p; p += sz_x;
    float* x2 = (float*)p; p += (size_t)NROWS * 4;
    float* w2 = (float*)p;

    // allow 128 KB dynamic LDS for k_gemm (host-side, idempotent, capture-safe)
    static int lds_ok = -1;
    if (lds_ok < 0)
      lds_ok = (int)hipFuncSetAttribute((const void*)k_gemm,
                                        hipFuncAttributeMaxDynamicSharedMemorySize,
                                        131072);

    k_zero<<<KDIM / 256, 256, 0, stream>>>(w2);
    k_wconv<<<dim3(KDIM / 64, CDIM / 64), 256, 0, stream>>>(w, whT, wlT, w2);
    k_xconv<<<(NROWS * CDIM) / 1024, 256, 0, stream>>>(x, xh);
    k_x2<<<NROWS, 64, 0, stream>>>(x, x2);
    k_gemm<<<256, 512, 131072, stream>>>(xh, whT, x2, w2, out);
    k_row<<<NROWS, 256, 0, stream>>>(out, stdp, x, whT, wlT, w2);
  } else {
    k_fb<<<dim3(NROWS / 64, KDIM / 64), 256, 0, stream>>>(x, w, out);
    k_row_fb<<<NROWS, 256, 0, stream>>>(out, stdp);
  }
}